// Round 2
// baseline (143.605 us; speedup 1.0000x reference)
//
#include <hip/hip_runtime.h>
#include <hip/hip_bf16.h>

typedef __bf16 bf16_t;
typedef __bf16 bf16x8 __attribute__((ext_vector_type(8)));
typedef __bf16 bf16x4 __attribute__((ext_vector_type(4)));
typedef float f32x4 __attribute__((ext_vector_type(4)));

#define FDIM 512
#define BM 64
#define NTHR 512

// Kernel 1: Qt[g][f] = bf16(Q[f][g])  (transpose + convert, 512x512)
__global__ void qtrans_kernel(const float* __restrict__ Q, bf16_t* __restrict__ Qt) {
    int idx = blockIdx.x * 256 + threadIdx.x;   // idx = g*512 + f
    int g = idx >> 9;
    int f = idx & 511;
    Qt[idx] = (bf16_t)Q[f * FDIM + g];
}

// Kernel 2: fused  out[b] = sum_g (x Q)[b,g] * x[b,g]
// 512 threads = 8 waves, BM=64 rows/block, 2 blocks/CU (66KB LDS, <=128 VGPR).
// Waves split N into 16 col-pairs of 32 cols; wave w owns pairs {w, 15-w}
// -> (w+1) + (16-w) = 17 K-steps per wave, perfectly balanced triangle skip.
__global__ __launch_bounds__(NTHR, 4) void bilinear_kernel(
    const float* __restrict__ x, const bf16_t* __restrict__ Qt,
    float* __restrict__ out)
{
    __shared__ bf16_t xs[BM * FDIM];   // 64 KB, XOR-swizzled (16B-chunk granular)
    __shared__ float rsum[8][BM];      // per-wave row partials

    const int tid = threadIdx.x;
    const size_t blk = (size_t)blockIdx.x * BM;
    const float4* xin = (const float4*)(x + blk * FDIM);

    // ---- stage x block: 16 float4/thread (64 VGPRs, no spill), then convert ----
    float4 v[16];
#pragma unroll
    for (int it = 0; it < 16; ++it) {
        v[it] = xin[it * NTHR + tid];
    }
#pragma unroll
    for (int it = 0; it < 16; ++it) {
        int e = (it * NTHR + tid) * 4;    // element offset (multiple of 4)
        int row = e >> 9;
        int se = e ^ ((row & 7) << 3);    // swizzle: XOR bits 3-5 (16B chunk id)
        bf16x4 b;
        b[0] = (bf16_t)v[it].x; b[1] = (bf16_t)v[it].y;
        b[2] = (bf16_t)v[it].z; b[3] = (bf16_t)v[it].w;
        *(bf16x4*)(xs + se) = b;
    }
    __syncthreads();

    const int w   = tid >> 6;
    const int l   = tid & 63;
    const int col = l & 15;   // A-frag row / B-frag col / D col
    const int kg  = l >> 4;   // k-group

    float rs[4][4];
#pragma unroll
    for (int m = 0; m < 4; ++m)
#pragma unroll
        for (int j = 0; j < 4; ++j) rs[m][j] = 0.0f;

    // wave w owns col-pairs {w, 15-w}: 17 K-steps total, uniform across waves
#pragma unroll
    for (int pi = 0; pi < 2; ++pi) {
        const int p  = (pi == 0) ? w : (15 - w);
        const int c0 = p * 32;
        const int nk = p + 1;

        f32x4 acc[2][4];
#pragma unroll
        for (int n = 0; n < 2; ++n)
#pragma unroll
            for (int m = 0; m < 4; ++m)
#pragma unroll
                for (int j = 0; j < 4; ++j) acc[n][m][j] = 0.0f;

        // B-frag base: Qt[(c0+col)][kg*8 + ks*32 ...], contiguous 16B per lane
        const bf16_t* qb0 = Qt + (size_t)(c0 + col) * FDIM + kg * 8;
        const bf16_t* qb1 = qb0 + 16 * FDIM;
        bf16x8 b0 = *(const bf16x8*)(qb0);
        bf16x8 b1 = *(const bf16x8*)(qb1);

        for (int ks = 0; ks < nk; ++ks) {
            bf16x8 nb0 = b0, nb1 = b1;
            if (ks + 1 < nk) {                       // prefetch next K-step
                nb0 = *(const bf16x8*)(qb0 + (ks + 1) * 32);
                nb1 = *(const bf16x8*)(qb1 + (ks + 1) * 32);
            }
            bf16x8 a[4];
#pragma unroll
            for (int m = 0; m < 4; ++m) {
                int r = m * 16 + col;
                int e = (r * FDIM + ks * 32 + kg * 8) ^ ((r & 7) << 3);
                a[m] = *(const bf16x8*)(xs + e);
            }
#pragma unroll
            for (int m = 0; m < 4; ++m) {
                acc[0][m] = __builtin_amdgcn_mfma_f32_16x16x32_bf16(a[m], b0, acc[0][m], 0, 0, 0);
                acc[1][m] = __builtin_amdgcn_mfma_f32_16x16x32_bf16(a[m], b1, acc[1][m], 0, 0, 0);
            }
            b0 = nb0; b1 = nb1;
        }

        // epilogue: rs += xQ_frag * x  (D layout: col = lane&15, row = kg*4 + j)
#pragma unroll
        for (int m = 0; m < 4; ++m) {
#pragma unroll
            for (int j = 0; j < 4; ++j) {
                int r  = m * 16 + kg * 4 + j;
                int e0 = (r * FDIM + c0 + col)      ^ ((r & 7) << 3);
                int e1 = (r * FDIM + c0 + 16 + col) ^ ((r & 7) << 3);
                rs[m][j] += acc[0][m][j] * (float)xs[e0]
                          + acc[1][m][j] * (float)xs[e1];
            }
        }
    }

    // ---- reduce: 16 lanes (same kg) hold different cols of the same rows ----
#pragma unroll
    for (int m = 0; m < 4; ++m) {
#pragma unroll
        for (int j = 0; j < 4; ++j) {
            float v2 = rs[m][j];
            v2 += __shfl_xor(v2, 1);
            v2 += __shfl_xor(v2, 2);
            v2 += __shfl_xor(v2, 4);
            v2 += __shfl_xor(v2, 8);
            rs[m][j] = v2;
        }
    }
    if (col == 0) {
#pragma unroll
        for (int m = 0; m < 4; ++m)
#pragma unroll
            for (int j = 0; j < 4; ++j)
                rsum[w][m * 16 + kg * 4 + j] = rs[m][j];
    }
    __syncthreads();

    if (tid < BM) {
        float s = 0.0f;
#pragma unroll
        for (int ww = 0; ww < 8; ++ww) s += rsum[ww][tid];
        out[blk + tid] = s;
    }
}

extern "C" void kernel_launch(void* const* d_in, const int* in_sizes, int n_in,
                              void* d_out, int out_size, void* d_ws, size_t ws_size,
                              hipStream_t stream) {
    const float* x = (const float*)d_in[0];
    const float* Q = (const float*)d_in[1];
    float* out = (float*)d_out;
    bf16_t* Qt = (bf16_t*)d_ws;        // needs 512*512*2 = 512 KB scratch

    const int B = in_sizes[0] / FDIM;  // 131072

    qtrans_kernel<<<(FDIM * FDIM) / 256, 256, 0, stream>>>(Q, Qt);
    bilinear_kernel<<<B / BM, NTHR, 0, stream>>>(x, Qt, out);
}

// Round 3
// 142.963 us; speedup vs baseline: 1.0045x; 1.0045x over previous
//
#include <hip/hip_runtime.h>
#include <hip/hip_bf16.h>

typedef __bf16 bf16_t;
typedef __bf16 bf16x8 __attribute__((ext_vector_type(8)));
typedef __bf16 bf16x4 __attribute__((ext_vector_type(4)));
typedef float f32x4 __attribute__((ext_vector_type(4)));

#define FDIM 512
#define BM 64
#define NTHR 512

// Kernel 1: Qt[g][f] = bf16(Q[f][g]) via LDS-tiled transpose (coalesced both sides)
__global__ void qtrans_kernel(const float* __restrict__ Q, bf16_t* __restrict__ Qt) {
    __shared__ float t[32][33];               // +1 pad: conflict-free transpose
    int tx = threadIdx.x & 31;                // column within tile
    int ty = threadIdx.x >> 5;                // row group (8 rows/pass)
    int f0 = blockIdx.x * 32;                 // tile origin in f
    int g0 = blockIdx.y * 32;                 // tile origin in g
#pragma unroll
    for (int i = 0; i < 4; ++i)               // read Q[f0+ty+8i][g0+tx] coalesced
        t[ty + 8 * i][tx] = Q[(size_t)(f0 + ty + 8 * i) * FDIM + g0 + tx];
    __syncthreads();
#pragma unroll
    for (int i = 0; i < 4; ++i)               // write Qt[g0+ty+8i][f0+tx] coalesced
        Qt[(size_t)(g0 + ty + 8 * i) * FDIM + f0 + tx] = (bf16_t)t[tx][ty + 8 * i];
}

// Kernel 2: fused  out[b] = sum_g (x Q)[b,g] * x[b,g]
// 512 threads = 8 waves, BM=64 rows/block, 2 blocks/CU (66KB LDS).
// Wave w owns col-pairs {w, 15-w} -> (w+1)+(16-w) = 17 K-steps, balanced.
__global__ __launch_bounds__(NTHR, 4) void bilinear_kernel(
    const float* __restrict__ x, const bf16_t* __restrict__ Qt,
    float* __restrict__ out)
{
    __shared__ bf16_t xs[BM * FDIM];   // 64 KB, XOR-swizzled (8B-chunk granular)
    __shared__ float rsum[8][BM];      // per-wave row partials

    const int tid = threadIdx.x;
    const size_t blk = (size_t)blockIdx.x * BM;
    const float4* xin = (const float4*)(x + blk * FDIM);

    // ---- stage x: 4 batches of 4 float4 (max 16 payload VGPRs live) ----
#pragma unroll 1
    for (int it = 0; it < 4; ++it) {
        float4 vv[4];
#pragma unroll
        for (int j = 0; j < 4; ++j) vv[j] = xin[(it * 4 + j) * NTHR + tid];
#pragma unroll
        for (int j = 0; j < 4; ++j) {
            int e = ((it * 4 + j) * NTHR + tid) * 4;  // element offset (mult of 4)
            int row = e >> 9;
            int se = e ^ ((row & 7) << 3);            // swizzle bits 3-5
            bf16x4 b;
            b[0] = (bf16_t)vv[j].x; b[1] = (bf16_t)vv[j].y;
            b[2] = (bf16_t)vv[j].z; b[3] = (bf16_t)vv[j].w;
            *(bf16x4*)(xs + se) = b;
        }
        __builtin_amdgcn_sched_barrier(0);  // forbid hoisting next batch's loads
    }
    __syncthreads();

    const int w   = tid >> 6;
    const int l   = tid & 63;
    const int col = l & 15;   // A-frag row / B-frag col / D col
    const int kg  = l >> 4;   // k-group

    float rs[4][4];
#pragma unroll
    for (int m = 0; m < 4; ++m)
#pragma unroll
        for (int j = 0; j < 4; ++j) rs[m][j] = 0.0f;

#pragma unroll
    for (int pi = 0; pi < 2; ++pi) {
        const int p  = (pi == 0) ? w : (15 - w);
        const int c0 = p * 32;
        const int nk = p + 1;

        f32x4 acc[2][4];
#pragma unroll
        for (int n = 0; n < 2; ++n)
#pragma unroll
            for (int m = 0; m < 4; ++m)
#pragma unroll
                for (int j = 0; j < 4; ++j) acc[n][m][j] = 0.0f;

        // B-frag base: Qt[(c0+col)][kg*8 + ks*32 ...], contiguous 16B per lane
        const bf16_t* qb0 = Qt + (size_t)(c0 + col) * FDIM + kg * 8;
        const bf16_t* qb1 = qb0 + 16 * FDIM;
        bf16x8 b0 = *(const bf16x8*)(qb0);
        bf16x8 b1 = *(const bf16x8*)(qb1);

        for (int ks = 0; ks < nk; ++ks) {
            bf16x8 nb0 = b0, nb1 = b1;
            if (ks + 1 < nk) {                       // prefetch next K-step
                nb0 = *(const bf16x8*)(qb0 + (ks + 1) * 32);
                nb1 = *(const bf16x8*)(qb1 + (ks + 1) * 32);
            }
            bf16x8 a[4];
#pragma unroll
            for (int m = 0; m < 4; ++m) {
                int r = m * 16 + col;
                int e = (r * FDIM + ks * 32 + kg * 8) ^ ((r & 7) << 3);
                a[m] = *(const bf16x8*)(xs + e);
            }
#pragma unroll
            for (int m = 0; m < 4; ++m) {
                acc[0][m] = __builtin_amdgcn_mfma_f32_16x16x32_bf16(a[m], b0, acc[0][m], 0, 0, 0);
                acc[1][m] = __builtin_amdgcn_mfma_f32_16x16x32_bf16(a[m], b1, acc[1][m], 0, 0, 0);
            }
            b0 = nb0; b1 = nb1;
        }

        // epilogue: rs += xQ_frag * x  (D layout: col = lane&15, row = kg*4 + j)
#pragma unroll
        for (int m = 0; m < 4; ++m) {
#pragma unroll
            for (int j = 0; j < 4; ++j) {
                int r  = m * 16 + kg * 4 + j;
                int e0 = (r * FDIM + c0 + col)      ^ ((r & 7) << 3);
                int e1 = (r * FDIM + c0 + 16 + col) ^ ((r & 7) << 3);
                rs[m][j] += acc[0][m][j] * (float)xs[e0]
                          + acc[1][m][j] * (float)xs[e1];
            }
        }
    }

    // ---- reduce: 16 lanes (same kg) hold different cols of the same rows ----
#pragma unroll
    for (int m = 0; m < 4; ++m) {
#pragma unroll
        for (int j = 0; j < 4; ++j) {
            float v2 = rs[m][j];
            v2 += __shfl_xor(v2, 1);
            v2 += __shfl_xor(v2, 2);
            v2 += __shfl_xor(v2, 4);
            v2 += __shfl_xor(v2, 8);
            rs[m][j] = v2;
        }
    }
    if (col == 0) {
#pragma unroll
        for (int m = 0; m < 4; ++m)
#pragma unroll
            for (int j = 0; j < 4; ++j)
                rsum[w][m * 16 + kg * 4 + j] = rs[m][j];
    }
    __syncthreads();

    if (tid < BM) {
        float s = 0.0f;
#pragma unroll
        for (int ww = 0; ww < 8; ++ww) s += rsum[ww][tid];
        out[blk + tid] = s;
    }
}

extern "C" void kernel_launch(void* const* d_in, const int* in_sizes, int n_in,
                              void* d_out, int out_size, void* d_ws, size_t ws_size,
                              hipStream_t stream) {
    const float* x = (const float*)d_in[0];
    const float* Q = (const float*)d_in[1];
    float* out = (float*)d_out;
    bf16_t* Qt = (bf16_t*)d_ws;        // needs 512*512*2 = 512 KB scratch

    const int B = in_sizes[0] / FDIM;  // 131072

    dim3 tgrid(FDIM / 32, FDIM / 32);
    qtrans_kernel<<<tgrid, 256, 0, stream>>>(Q, Qt);
    bilinear_kernel<<<B / BM, NTHR, 0, stream>>>(x, Qt, out);
}

// Round 4
// 111.093 us; speedup vs baseline: 1.2927x; 1.2869x over previous
//
#include <hip/hip_runtime.h>
#include <hip/hip_bf16.h>

typedef __bf16 bf16_t;
typedef __bf16 bf16x8 __attribute__((ext_vector_type(8)));
typedef __bf16 bf16x4 __attribute__((ext_vector_type(4)));
typedef float f32x4 __attribute__((ext_vector_type(4)));

#define FDIM 512
#define BM 64
#define NTHR 512

// Kernel 1: Qt[g][f] = bf16(Q[f][g]) via LDS-tiled transpose (coalesced both sides)
__global__ void qtrans_kernel(const float* __restrict__ Q, bf16_t* __restrict__ Qt) {
    __shared__ float t[32][33];               // +1 pad: conflict-free transpose
    int tx = threadIdx.x & 31;
    int ty = threadIdx.x >> 5;
    int f0 = blockIdx.x * 32;
    int g0 = blockIdx.y * 32;
#pragma unroll
    for (int i = 0; i < 4; ++i)
        t[ty + 8 * i][tx] = Q[(size_t)(f0 + ty + 8 * i) * FDIM + g0 + tx];
    __syncthreads();
#pragma unroll
    for (int i = 0; i < 4; ++i)
        Qt[(size_t)(g0 + ty + 8 * i) * FDIM + f0 + tx] = (bf16_t)t[tx][ty + 8 * i];
}

// Kernel 2: fused  out[b] = sum_g (x Q)[b,g] * x[b,g]
// 512 threads = 8 waves, BM=64 rows/block, 2 blocks/CU (66KB LDS).
// Wave w owns col-pairs {w, 15-w}, processed as FOUR sequential 16-col halves
// so only acc[4] (16 regs) is live at a time -> fits the 128-reg/wave budget
// (launch_bounds 512,4) with zero scratch spill.
__global__ __launch_bounds__(NTHR, 4) void bilinear_kernel(
    const float* __restrict__ x, const bf16_t* __restrict__ Qt,
    float* __restrict__ out)
{
    __shared__ bf16_t xs[BM * FDIM];   // 64 KB, XOR-swizzled: elem ^= (row&7)<<3
    __shared__ float rsum[8][BM];      // per-wave row partials

    const int tid = threadIdx.x;
    const size_t blk = (size_t)blockIdx.x * BM;
    const float4* xin = (const float4*)(x + blk * FDIM);

    // ---- stage x: 4 batches of 4 float4 ----
#pragma unroll 1
    for (int it = 0; it < 4; ++it) {
        float4 vv[4];
#pragma unroll
        for (int j = 0; j < 4; ++j) vv[j] = xin[(it * 4 + j) * NTHR + tid];
#pragma unroll
        for (int j = 0; j < 4; ++j) {
            int e = ((it * 4 + j) * NTHR + tid) * 4;
            int row = e >> 9;
            int se = e ^ ((row & 7) << 3);
            bf16x4 b;
            b[0] = (bf16_t)vv[j].x; b[1] = (bf16_t)vv[j].y;
            b[2] = (bf16_t)vv[j].z; b[3] = (bf16_t)vv[j].w;
            *(bf16x4*)(xs + se) = b;
        }
        __builtin_amdgcn_sched_barrier(0);
    }
    __syncthreads();

    const int w   = tid >> 6;
    const int l   = tid & 63;
    const int col = l & 15;   // A-frag row / B-frag col / D col
    const int kg  = l >> 4;   // k-group

    float rs[4][4];
#pragma unroll
    for (int m = 0; m < 4; ++m)
#pragma unroll
        for (int j = 0; j < 4; ++j) rs[m][j] = 0.0f;

    // 4 half-pair iterations: (p=w,h=0),(p=w,h=1),(p=15-w,h=0),(p=15-w,h=1)
#pragma unroll 1
    for (int pi = 0; pi < 4; ++pi) {
        const int p  = (pi < 2) ? w : (15 - w);
        const int h  = pi & 1;
        const int c0 = p * 32 + h * 16;    // 16-col half origin
        const int nk = p + 1;              // K-steps for this pair (triangle)

        f32x4 acc[4];
#pragma unroll
        for (int m = 0; m < 4; ++m)
#pragma unroll
            for (int j = 0; j < 4; ++j) acc[m][j] = 0.0f;

        // B-frag: Qt[(c0+col)][ks*32 + kg*8 ...], contiguous 16B per lane
        const bf16_t* qb = Qt + (size_t)(c0 + col) * FDIM + kg * 8;
        bf16x8 b0 = *(const bf16x8*)(qb);

        for (int ks = 0; ks < nk; ++ks) {
            bf16x8 nb = b0;
            if (ks + 1 < nk) nb = *(const bf16x8*)(qb + (ks + 1) * 32);
            bf16x8 a[4];
#pragma unroll
            for (int m = 0; m < 4; ++m) {
                int r = m * 16 + col;
                int e = (r * FDIM + ks * 32 + kg * 8) ^ ((r & 7) << 3);
                a[m] = *(const bf16x8*)(xs + e);
            }
#pragma unroll
            for (int m = 0; m < 4; ++m)
                acc[m] = __builtin_amdgcn_mfma_f32_16x16x32_bf16(a[m], b0, acc[m], 0, 0, 0);
            b0 = nb;
        }

        // epilogue: rs += xQ_frag * x  (D layout: col = lane&15, row = kg*4 + j)
#pragma unroll
        for (int m = 0; m < 4; ++m) {
#pragma unroll
            for (int j = 0; j < 4; ++j) {
                int r = m * 16 + kg * 4 + j;
                int e = (r * FDIM + c0 + col) ^ ((r & 7) << 3);
                rs[m][j] += acc[m][j] * (float)xs[e];
            }
        }
    }

    // ---- reduce: 16 lanes (same kg) hold different cols of the same rows ----
#pragma unroll
    for (int m = 0; m < 4; ++m) {
#pragma unroll
        for (int j = 0; j < 4; ++j) {
            float v2 = rs[m][j];
            v2 += __shfl_xor(v2, 1);
            v2 += __shfl_xor(v2, 2);
            v2 += __shfl_xor(v2, 4);
            v2 += __shfl_xor(v2, 8);
            rs[m][j] = v2;
        }
    }
    if (col == 0) {
#pragma unroll
        for (int m = 0; m < 4; ++m)
#pragma unroll
            for (int j = 0; j < 4; ++j)
                rsum[w][m * 16 + kg * 4 + j] = rs[m][j];
    }
    __syncthreads();

    if (tid < BM) {
        float s = 0.0f;
#pragma unroll
        for (int ww = 0; ww < 8; ++ww) s += rsum[ww][tid];
        out[blk + tid] = s;
    }
}

extern "C" void kernel_launch(void* const* d_in, const int* in_sizes, int n_in,
                              void* d_out, int out_size, void* d_ws, size_t ws_size,
                              hipStream_t stream) {
    const float* x = (const float*)d_in[0];
    const float* Q = (const float*)d_in[1];
    float* out = (float*)d_out;
    bf16_t* Qt = (bf16_t*)d_ws;        // needs 512*512*2 = 512 KB scratch

    const int B = in_sizes[0] / FDIM;  // 131072

    dim3 tgrid(FDIM / 32, FDIM / 32);
    qtrans_kernel<<<tgrid, 256, 0, stream>>>(Q, Qt);
    bilinear_kernel<<<B / BM, NTHR, 0, stream>>>(x, Qt, out);
}